// Round 6
// baseline (160.927 us; speedup 1.0000x reference)
//
#include <hip/hip_runtime.h>
#include <hip/hip_bf16.h>
#include <math.h>

typedef _Float16 half8 __attribute__((ext_vector_type(8)));
typedef _Float16 half4_t __attribute__((ext_vector_type(4)));
typedef _Float16 half2_t __attribute__((ext_vector_type(2)));
typedef float floatx4 __attribute__((ext_vector_type(4)));
typedef float floatx2 __attribute__((ext_vector_type(2)));

#define MFMA16(a, b, c) __builtin_amdgcn_mfma_f32_16x16x32_f16(a, b, c, 0, 0, 0)
#define MASKVAL (-30000.0f)
// 1/sqrt(128) * log2(e), folded into wqt during prep
#define QSCALE 0.1275261529f

// ---------------------------------------------------------------------------
// Kernel 1: coalesced LDS-tiled weight transpose + fp32->fp16 convert.
// ---------------------------------------------------------------------------
__global__ __launch_bounds__(256) void wprep(
    const float* __restrict__ wq, const float* __restrict__ wk,
    const float* __restrict__ wv, const float* __restrict__ wo,
    _Float16* __restrict__ wqt, _Float16* __restrict__ wkt,
    _Float16* __restrict__ wvt, _Float16* __restrict__ wot) {
  __shared__ float T[32][36];
  int bx = blockIdx.x, tid = threadIdx.x;
  const float* src;
  _Float16* dst;
  int R, C, r0, c0;
  float sc = 1.0f;
  if (bx < 384) {
    int p = bx >> 7, t = bx & 127;
    src = (p == 0) ? wq : (p == 1) ? wk : wv;
    dst = (p == 0) ? wqt : (p == 1) ? wkt : wvt;
    if (p == 0) sc = QSCALE;
    R = 1024; C = 128;
    r0 = (t & 31) * 32; c0 = (t >> 5) * 32;
  } else {
    int t = bx - 384;
    src = wo; dst = wot;
    R = 128; C = 1024;
    r0 = (t & 3) * 32; c0 = (t >> 2) * 32;
  }
  {
    int row = tid >> 3, c4 = (tid & 7) * 4;
    float4 f = *(const float4*)&src[(size_t)(r0 + row) * C + c0 + c4];
    T[row][c4] = f.x; T[row][c4 + 1] = f.y; T[row][c4 + 2] = f.z; T[row][c4 + 3] = f.w;
  }
  __syncthreads();
  {
    int cc = tid >> 3, r4 = (tid & 7) * 4;
    half4_t h;
    h[0] = (_Float16)(T[r4 + 0][cc] * sc);
    h[1] = (_Float16)(T[r4 + 1][cc] * sc);
    h[2] = (_Float16)(T[r4 + 2][cc] * sc);
    h[3] = (_Float16)(T[r4 + 3][cc] * sc);
    *(half4_t*)&dst[(size_t)(c0 + cc) * R + r0 + r4] = h;
  }
}

// ---------------------------------------------------------------------------
// Kernel 2: FUSED QKV projection, x read once (R3 config, best measured:
// 256 blocks x 512 threads, 32-row x 384-col tiles, BK=64). Wave = 32x48
// sub-tile. Register prefetch double-buffer. V transposed through LDS for
// coalesced stores.
// ---------------------------------------------------------------------------
__global__ __launch_bounds__(512, 4) void qkv_fused(
    const float* __restrict__ x, const _Float16* __restrict__ wqt,
    const _Float16* __restrict__ wkt, const _Float16* __restrict__ wvt,
    _Float16* __restrict__ Qh, _Float16* __restrict__ Kh,
    _Float16* __restrict__ Vt) {
  __shared__ _Float16 A_lds[32 * 72];
  __shared__ _Float16 B_lds[384 * 72];
  int tid = threadIdx.x;
  int w = tid >> 6, lane = tid & 63, quad = lane >> 4, l16 = lane & 15;
  int m0 = blockIdx.x * 32;
  floatx4 zero = {0.f, 0.f, 0.f, 0.f};
  floatx4 acc[2][3];
#pragma unroll
  for (int mi = 0; mi < 2; mi++)
#pragma unroll
    for (int ni = 0; ni < 3; ni++) acc[mi][ni] = zero;

  int arow = tid >> 4, ac0 = (tid & 15) * 4;   // A: 32 rows, 4 floats/thr
  int brow = tid >> 2, bc0 = (tid & 3) * 16;   // B: 128 rows/proj, 16 halfs/thr/proj

  const float* asrc = x + (size_t)(m0 + arow) * 1024 + ac0;
  const _Float16* bsrc0 = wqt + (size_t)brow * 1024 + bc0;
  const _Float16* bsrc1 = wkt + (size_t)brow * 1024 + bc0;
  const _Float16* bsrc2 = wvt + (size_t)brow * 1024 + bc0;

  float4 af;
  half8 bf[3][2];
  af = *(const float4*)asrc;
#pragma unroll
  for (int i = 0; i < 2; i++) {
    bf[0][i] = *(const half8*)(bsrc0 + i * 8);
    bf[1][i] = *(const half8*)(bsrc1 + i * 8);
    bf[2][i] = *(const half8*)(bsrc2 + i * 8);
  }

  for (int k0 = 0; k0 < 1024; k0 += 64) {
    {
      half4_t h;
      h[0] = (_Float16)af.x; h[1] = (_Float16)af.y;
      h[2] = (_Float16)af.z; h[3] = (_Float16)af.w;
      *(half4_t*)&A_lds[arow * 72 + ac0] = h;
    }
#pragma unroll
    for (int p = 0; p < 3; p++)
#pragma unroll
      for (int i = 0; i < 2; i++)
        *(half8*)&B_lds[(p * 128 + brow) * 72 + bc0 + i * 8] = bf[p][i];
    __syncthreads();

    // prefetch next k-slice into registers (latency overlaps MFMA phase)
    if (k0 + 64 < 1024) {
      af = *(const float4*)(asrc + k0 + 64);
#pragma unroll
      for (int i = 0; i < 2; i++) {
        bf[0][i] = *(const half8*)(bsrc0 + k0 + 64 + i * 8);
        bf[1][i] = *(const half8*)(bsrc1 + k0 + 64 + i * 8);
        bf[2][i] = *(const half8*)(bsrc2 + k0 + 64 + i * 8);
      }
    }

    half8 a[2][2];
#pragma unroll
    for (int mi = 0; mi < 2; mi++)
#pragma unroll
      for (int kc = 0; kc < 2; kc++)
        a[mi][kc] = *(const half8*)&A_lds[(mi * 16 + l16) * 72 + kc * 32 + quad * 8];
    int nw = w * 48;
#pragma unroll
    for (int ni = 0; ni < 3; ni++)
#pragma unroll
      for (int kc = 0; kc < 2; kc++) {
        half8 b = *(const half8*)&B_lds[(nw + ni * 16 + l16) * 72 + kc * 32 + quad * 8];
        acc[0][ni] = MFMA16(a[0][kc], b, acc[0][ni]);
        acc[1][ni] = MFMA16(a[1][kc], b, acc[1][ni]);
      }
    __syncthreads();
  }

  // Epilogue: Q/K stored directly; V columns go through LDS transpose.
  _Float16* Vl = B_lds;  // [128 cols][pad 40]; B_lds dead after last barrier
#pragma unroll
  for (int mi = 0; mi < 2; mi++)
#pragma unroll
    for (int ni = 0; ni < 3; ni++) {
      int nb = w * 48 + ni * 16;
#pragma unroll
      for (int r = 0; r < 4; r++) {
        int row = m0 + mi * 16 + quad * 4 + r;
        _Float16 v = (_Float16)acc[mi][ni][r];
        if (nb < 128)
          Qh[(size_t)row * 128 + nb + l16] = v;
        else if (nb < 256)
          Kh[(size_t)row * 128 + nb - 128 + l16] = v;
        else
          Vl[(nb - 256 + l16) * 40 + mi * 16 + quad * 4 + r] = v;
      }
    }
  __syncthreads();
  if (tid < 256) {
    int col = tid >> 1, hh = tid & 1;
    int bb = m0 >> 11, s0 = (m0 & 2047) + hh * 16;
    half8 h0 = *(half8*)&Vl[col * 40 + hh * 16];
    half8 h1 = *(half8*)&Vl[col * 40 + hh * 16 + 8];
    _Float16* dstv = Vt + ((size_t)(bb * 128 + col)) * 2048 + s0;
    *(half8*)&dstv[0] = h0;
    *(half8*)&dstv[8] = h1;
  }
}

// ---------------------------------------------------------------------------
// Kernel 3: flash-attention partial, one 256-key chunk per block (two
// 128-key sub-chunks, online softmax). 576 blocks, all co-resident at 3
// blocks/CU (R4 parallelism -- R5's 512-key chunks doubled the critical
// path and regressed). NEW: causal-mask compare/cndmask pass is skipped for
// sub-chunks strictly below the diagonal (block-uniform branch; ~78% of
// sub-chunks), and the O-rescale pass is skipped on the first sub-chunk
// (O is all-zero).
// ---------------------------------------------------------------------------
__global__ __launch_bounds__(256, 3) void attn_partial(
    const _Float16* __restrict__ Qh, const _Float16* __restrict__ Kh,
    const _Float16* __restrict__ Vt, _Float16* __restrict__ Opart,
    float* __restrict__ Ml) {
  __shared__ _Float16 KV_lds[128 * 136];  // K (key-major), then V (feat-major)
  __shared__ _Float16 P_lds[4 * 16 * 136];
  int tid = threadIdx.x;
  int w = tid >> 6, lane = tid & 63, quad = lane >> 4, l16 = lane & 15;
  int g = (int)blockIdx.x;
  int b = g & 3;
  int r = g >> 2;  // 0..143: group m has 4 qtiles x (m+1) chunks, offset 2m(m+1)
  int m = (int)sqrtf((float)r * 0.5f);
  while (2 * m * (m + 1) > r) m--;
  while (2 * (m + 1) * (m + 2) <= r) m++;
  int r0_ = r - 2 * m * (m + 1);
  int qdiv = r0_ / (m + 1);
  int qt = 4 * m + qdiv;
  int kc = r0_ - qdiv * (m + 1);
  int q0 = qt * 64, k0 = kc * 256;
  int kmax = (qt + 1) * 64;
  int len = kmax - k0; if (len > 256) len = 256;
  int nsub = (len + 127) >> 7;  // 1 or 2
  int qw0 = q0 + w * 16;
  int sidx = (b * 32 + qt) * 8 + kc;

  const _Float16* Kb = Kh + (size_t)b * 2048 * 128;
  const _Float16* Vb = Vt + (size_t)b * 128 * 2048;

  half8 aq[4];
  {
    const _Float16* qbase = Qh + (size_t)(b * 2048 + qw0 + l16) * 128;
#pragma unroll
    for (int c = 0; c < 4; c++) aq[c] = *(const half8*)&qbase[c * 32 + quad * 8];
  }

  int srow = tid >> 1, scol = (tid & 1) * 64;
  floatx4 zero = {0.f, 0.f, 0.f, 0.f};
  floatx4 O[8];
#pragma unroll
  for (int t = 0; t < 8; t++) O[t] = zero;
  float m_r[4] = {MASKVAL, MASKVAL, MASKVAL, MASKVAL};
  float l_r[4] = {0.f, 0.f, 0.f, 0.f};

  for (int s = 0; s < nsub; s++) {
    int ks = k0 + s * 128;
    bool diag = (ks + 128 > q0);  // block-uniform: sub-chunk touches diagonal
    if (s) __syncthreads();  // prev PV done with KV_lds/P_lds
#pragma unroll
    for (int i = 0; i < 8; i++)
      *(half8*)&KV_lds[srow * 136 + scol + i * 8] =
          *(const half8*)&Kb[(size_t)(ks + srow) * 128 + scol + i * 8];
    half8 vreg[8];
#pragma unroll
    for (int i = 0; i < 8; i++)
      vreg[i] = *(const half8*)&Vb[(size_t)srow * 2048 + ks + scol + i * 8];
    __syncthreads();

    floatx4 sa[8];
#pragma unroll
    for (int t = 0; t < 8; t++) sa[t] = zero;
#pragma unroll
    for (int t = 0; t < 8; t++)
#pragma unroll
      for (int c = 0; c < 4; c++) {
        half8 bk = *(const half8*)&KV_lds[(t * 16 + l16) * 136 + c * 32 + quad * 8];
        sa[t] = MFMA16(aq[c], bk, sa[t]);
      }

    float sc[4];
    if (diag) {
#pragma unroll
      for (int j = 0; j < 4; j++) {
        int query = qw0 + quad * 4 + j;
        float mx = MASKVAL;
#pragma unroll
        for (int t = 0; t < 8; t++) {
          float v = (ks + t * 16 + l16 > query) ? MASKVAL : sa[t][j];
          sa[t][j] = v;
          mx = fmaxf(mx, v);
        }
#pragma unroll
        for (int off = 1; off < 16; off <<= 1) mx = fmaxf(mx, __shfl_xor(mx, off));
        float mnew = fmaxf(m_r[j], mx);
        float scj = exp2f(m_r[j] - mnew);
        float rs = 0.f;
#pragma unroll
        for (int t = 0; t < 8; t++) {
          float e = exp2f(sa[t][j] - mnew);
          sa[t][j] = e;
          rs += e;
        }
#pragma unroll
        for (int off = 1; off < 16; off <<= 1) rs += __shfl_xor(rs, off);
        l_r[j] = l_r[j] * scj + rs;
        m_r[j] = mnew;
        sc[j] = scj;
      }
    } else {
#pragma unroll
      for (int j = 0; j < 4; j++) {
        float mx = MASKVAL;
#pragma unroll
        for (int t = 0; t < 8; t++) mx = fmaxf(mx, sa[t][j]);
#pragma unroll
        for (int off = 1; off < 16; off <<= 1) mx = fmaxf(mx, __shfl_xor(mx, off));
        float mnew = fmaxf(m_r[j], mx);
        float scj = exp2f(m_r[j] - mnew);
        float rs = 0.f;
#pragma unroll
        for (int t = 0; t < 8; t++) {
          float e = exp2f(sa[t][j] - mnew);
          sa[t][j] = e;
          rs += e;
        }
#pragma unroll
        for (int off = 1; off < 16; off <<= 1) rs += __shfl_xor(rs, off);
        l_r[j] = l_r[j] * scj + rs;
        m_r[j] = mnew;
        sc[j] = scj;
      }
    }
    // rescale running O by per-row correction (skip on first sub-chunk: O=0)
    if (s) {
#pragma unroll
      for (int t = 0; t < 8; t++)
#pragma unroll
        for (int j = 0; j < 4; j++) O[t][j] *= sc[j];
    }

    __syncthreads();  // all waves done reading K from KV_lds
#pragma unroll
    for (int i = 0; i < 8; i++)
      *(half8*)&KV_lds[srow * 136 + scol + i * 8] = vreg[i];
    _Float16* P = P_lds + w * 16 * 136;
#pragma unroll
    for (int j = 0; j < 4; j++)
#pragma unroll
      for (int t = 0; t < 8; t++)
        P[(quad * 4 + j) * 136 + t * 16 + l16] = (_Float16)sa[t][j];
    __syncthreads();  // V,P visible to all waves

#pragma unroll
    for (int c2 = 0; c2 < 4; c2++) {
      half8 ap = *(const half8*)&P[l16 * 136 + c2 * 32 + quad * 8];
#pragma unroll
      for (int t = 0; t < 8; t++) {
        half8 bv = *(const half8*)&KV_lds[(t * 16 + l16) * 136 + c2 * 32 + quad * 8];
        O[t] = MFMA16(ap, bv, O[t]);
      }
    }
  }

  size_t obase = (size_t)sidx * 8192;
#pragma unroll
  for (int t = 0; t < 8; t++)
#pragma unroll
    for (int j = 0; j < 4; j++)
      Opart[obase + (size_t)(w * 16 + quad * 4 + j) * 128 + t * 16 + l16] = (_Float16)O[t][j];
  if (l16 == 0)
#pragma unroll
    for (int j = 0; j < 4; j++) {
      int row = w * 16 + quad * 4 + j;
      floatx2 ml;
      ml[0] = m_r[j];
      ml[1] = l_r[j];
      *(floatx2*)&Ml[(size_t)sidx * 128 + row * 2] = ml;
    }
}

// ---------------------------------------------------------------------------
// Kernel 4 (fused combine + out-projection): 256 blocks x 32 rows (R3
// config, best measured). Combine <=8 partials into LDS ctx tile, then
// GEMM vs wot over 8 n-chunks with register-prefetched B staging.
// ---------------------------------------------------------------------------
__global__ __launch_bounds__(256) void combine_out(
    const _Float16* __restrict__ Opart, const float* __restrict__ Ml,
    const _Float16* __restrict__ wot, float* __restrict__ out) {
  __shared__ _Float16 A_lds[32 * 136];
  __shared__ _Float16 B_lds[128 * 136];
  int tid = threadIdx.x;
  int r0 = blockIdx.x * 32;
  int b = r0 >> 11, s0 = r0 & 2047;
  int qt = s0 >> 6, rbase = s0 & 63;
  int nkc = (qt + 4) >> 2;  // ceil((qt+1)/4), block-uniform
  int sidx0 = (b * 32 + qt) * 8;

  {  // ---- combine phase: each thread = 1 row x 16 cols ----
    int lr = tid >> 3, c0 = (tid & 7) * 16;
    int ri = rbase + lr;
    float mv[8], lv[8];
#pragma unroll
    for (int i = 0; i < 8; i++) {
      if (i < nkc) {
        floatx2 ml = *(const floatx2*)&Ml[(size_t)(sidx0 + i) * 128 + ri * 2];
        mv[i] = ml[0]; lv[i] = ml[1];
      } else { mv[i] = MASKVAL; lv[i] = 0.f; }
    }
    float M = MASKVAL;
#pragma unroll
    for (int i = 0; i < 8; i++) M = fmaxf(M, mv[i]);
    float L = 0.f;
    float a0[16];
#pragma unroll
    for (int c = 0; c < 16; c++) a0[c] = 0.f;
#pragma unroll
    for (int i = 0; i < 8; i++) {
      if (i < nkc) {
        float scv = exp2f(mv[i] - M);
        L += lv[i] * scv;
        const _Float16* op = &Opart[(size_t)(sidx0 + i) * 8192 + (size_t)ri * 128 + c0];
        half8 o0 = *(const half8*)&op[0];
        half8 o1 = *(const half8*)&op[8];
#pragma unroll
        for (int c = 0; c < 8; c++) {
          a0[c]     += scv * (float)o0[c];
          a0[8 + c] += scv * (float)o1[c];
        }
      }
    }
    float inv = 1.f / L;
    half8 h0, h1;
#pragma unroll
    for (int c = 0; c < 8; c++) {
      h0[c] = (_Float16)(a0[c] * inv);
      h1[c] = (_Float16)(a0[8 + c] * inv);
    }
    *(half8*)&A_lds[lr * 136 + c0] = h0;
    *(half8*)&A_lds[lr * 136 + c0 + 8] = h1;
  }

  int w = tid >> 6, lane = tid & 63, quad = lane >> 4, l16 = lane & 15;
  int bn = tid >> 1, bk = (tid & 1) * 64;
  half8 bf[8];
#pragma unroll
  for (int i = 0; i < 8; i++)
    bf[i] = *(const half8*)&wot[(size_t)bn * 128 + bk + i * 8];
  __syncthreads();  // A_lds ready

  half8 a[2][4];
#pragma unroll
  for (int c = 0; c < 4; c++) {
    a[0][c] = *(const half8*)&A_lds[l16 * 136 + c * 32 + quad * 8];
    a[1][c] = *(const half8*)&A_lds[(16 + l16) * 136 + c * 32 + quad * 8];
  }
  floatx4 zero = {0.f, 0.f, 0.f, 0.f};
  for (int nc = 0; nc < 8; nc++) {
#pragma unroll
    for (int i = 0; i < 8; i++)
      *(half8*)&B_lds[bn * 136 + bk + i * 8] = bf[i];
    __syncthreads();
    if (nc < 7) {
#pragma unroll
      for (int i = 0; i < 8; i++)
        bf[i] = *(const half8*)&wot[(size_t)((nc + 1) * 128 + bn) * 128 + bk + i * 8];
    }
    floatx4 acc[2][2];
#pragma unroll
    for (int mi = 0; mi < 2; mi++)
#pragma unroll
      for (int ni = 0; ni < 2; ni++) acc[mi][ni] = zero;
    int nw = w * 32;
#pragma unroll
    for (int ni = 0; ni < 2; ni++)
#pragma unroll
      for (int c = 0; c < 4; c++) {
        half8 bb = *(const half8*)&B_lds[(nw + ni * 16 + l16) * 136 + c * 32 + quad * 8];
        acc[0][ni] = MFMA16(a[0][c], bb, acc[0][ni]);
        acc[1][ni] = MFMA16(a[1][c], bb, acc[1][ni]);
      }
#pragma unroll
    for (int mi = 0; mi < 2; mi++)
#pragma unroll
      for (int ni = 0; ni < 2; ni++)
#pragma unroll
        for (int r = 0; r < 4; r++) {
          int row = r0 + mi * 16 + quad * 4 + r;
          out[(size_t)row * 1024 + nc * 128 + nw + ni * 16 + l16] = acc[mi][ni][r];
        }
    __syncthreads();
  }
}

// ---------------------------------------------------------------------------
extern "C" void kernel_launch(void* const* d_in, const int* in_sizes, int n_in,
                              void* d_out, int out_size, void* d_ws, size_t ws_size,
                              hipStream_t stream) {
  const float* x = (const float*)d_in[0];
  const float* wq = (const float*)d_in[1];
  const float* wk = (const float*)d_in[2];
  const float* wv = (const float*)d_in[3];
  const float* wo = (const float*)d_in[4];
  char* ws = (char*)d_ws;
  _Float16* wqt = (_Float16*)(ws + 0);
  _Float16* wkt = (_Float16*)(ws + 262144);
  _Float16* wvt = (_Float16*)(ws + 524288);
  _Float16* wot = (_Float16*)(ws + 786432);
  _Float16* Qh  = (_Float16*)(ws + 1048576);              // 2 MB
  _Float16* Kh  = (_Float16*)(ws + 3145728);              // 2 MB
  _Float16* Vt  = (_Float16*)(ws + 5242880);              // 2 MB
  _Float16* Opart = (_Float16*)(ws + 9437184);            // 1024 x 16 KB = 16 MB
  float* Ml = (float*)(ws + 26214400);                    // 512 KB
  float* out = (float*)d_out;

  wprep<<<512, 256, 0, stream>>>(wq, wk, wv, wo, wqt, wkt, wvt, wot);
  qkv_fused<<<256, 512, 0, stream>>>(x, wqt, wkt, wvt, Qh, Kh, Vt);
  attn_partial<<<576, 256, 0, stream>>>(Qh, Kh, Vt, Opart, Ml);
  combine_out<<<256, 256, 0, stream>>>(Opart, Ml, wot, out);
}

// Round 7
// 148.592 us; speedup vs baseline: 1.0830x; 1.0830x over previous
//
#include <hip/hip_runtime.h>
#include <hip/hip_bf16.h>
#include <math.h>

typedef _Float16 half8 __attribute__((ext_vector_type(8)));
typedef _Float16 half4_t __attribute__((ext_vector_type(4)));
typedef _Float16 half2_t __attribute__((ext_vector_type(2)));
typedef float floatx4 __attribute__((ext_vector_type(4)));
typedef float floatx2 __attribute__((ext_vector_type(2)));

#define MFMA16(a, b, c) __builtin_amdgcn_mfma_f32_16x16x32_f16(a, b, c, 0, 0, 0)
#define MASKVAL (-30000.0f)
// 1/sqrt(128) * log2(e), folded into wqt during prep
#define QSCALE 0.1275261529f

// ---------------------------------------------------------------------------
// Kernel 1: coalesced LDS-tiled weight transpose + fp32->fp16 convert.
// ---------------------------------------------------------------------------
__global__ __launch_bounds__(256) void wprep(
    const float* __restrict__ wq, const float* __restrict__ wk,
    const float* __restrict__ wv, const float* __restrict__ wo,
    _Float16* __restrict__ wqt, _Float16* __restrict__ wkt,
    _Float16* __restrict__ wvt, _Float16* __restrict__ wot) {
  __shared__ float T[32][36];
  int bx = blockIdx.x, tid = threadIdx.x;
  const float* src;
  _Float16* dst;
  int R, C, r0, c0;
  float sc = 1.0f;
  if (bx < 384) {
    int p = bx >> 7, t = bx & 127;
    src = (p == 0) ? wq : (p == 1) ? wk : wv;
    dst = (p == 0) ? wqt : (p == 1) ? wkt : wvt;
    if (p == 0) sc = QSCALE;
    R = 1024; C = 128;
    r0 = (t & 31) * 32; c0 = (t >> 5) * 32;
  } else {
    int t = bx - 384;
    src = wo; dst = wot;
    R = 128; C = 1024;
    r0 = (t & 3) * 32; c0 = (t >> 2) * 32;
  }
  {
    int row = tid >> 3, c4 = (tid & 7) * 4;
    float4 f = *(const float4*)&src[(size_t)(r0 + row) * C + c0 + c4];
    T[row][c4] = f.x; T[row][c4 + 1] = f.y; T[row][c4 + 2] = f.z; T[row][c4 + 3] = f.w;
  }
  __syncthreads();
  {
    int cc = tid >> 3, r4 = (tid & 7) * 4;
    half4_t h;
    h[0] = (_Float16)(T[r4 + 0][cc] * sc);
    h[1] = (_Float16)(T[r4 + 1][cc] * sc);
    h[2] = (_Float16)(T[r4 + 2][cc] * sc);
    h[3] = (_Float16)(T[r4 + 3][cc] * sc);
    *(half4_t*)&dst[(size_t)(c0 + cc) * R + r0 + r4] = h;
  }
}

// ---------------------------------------------------------------------------
// Kernel 2: FUSED QKV projection -- reads x exactly ONCE. 256 blocks x 512
// threads (8 waves). Tile: 32 rows x 384 cols (Q|K|V). BK=64, 16 k-steps.
// LDS: A[32x72] + B[384x72] fp16 = 60 KB. Each wave: 32x48 sub-tile
// (2m x 3n; 12 MFMA, 4 A + 6 B ds_read_b128 per k-step). Register-prefetch
// double buffer. V columns transposed through LDS for coalesced Vt stores.
// ---------------------------------------------------------------------------
__global__ __launch_bounds__(512, 4) void qkv_fused(
    const float* __restrict__ x, const _Float16* __restrict__ wqt,
    const _Float16* __restrict__ wkt, const _Float16* __restrict__ wvt,
    _Float16* __restrict__ Qh, _Float16* __restrict__ Kh,
    _Float16* __restrict__ Vt) {
  __shared__ _Float16 A_lds[32 * 72];
  __shared__ _Float16 B_lds[384 * 72];
  int tid = threadIdx.x;
  int w = tid >> 6, lane = tid & 63, quad = lane >> 4, l16 = lane & 15;
  int m0 = blockIdx.x * 32;
  floatx4 zero = {0.f, 0.f, 0.f, 0.f};
  floatx4 acc[2][3];
#pragma unroll
  for (int mi = 0; mi < 2; mi++)
#pragma unroll
    for (int ni = 0; ni < 3; ni++) acc[mi][ni] = zero;

  int arow = tid >> 4, ac0 = (tid & 15) * 4;   // A: 32 rows, 4 floats/thr
  int brow = tid >> 2, bc0 = (tid & 3) * 16;   // B: 128 rows/proj, 16 halfs/thr/proj

  const float* asrc = x + (size_t)(m0 + arow) * 1024 + ac0;
  const _Float16* bsrc0 = wqt + (size_t)brow * 1024 + bc0;
  const _Float16* bsrc1 = wkt + (size_t)brow * 1024 + bc0;
  const _Float16* bsrc2 = wvt + (size_t)brow * 1024 + bc0;

  float4 af;
  half8 bf[3][2];
  af = *(const float4*)asrc;
#pragma unroll
  for (int i = 0; i < 2; i++) {
    bf[0][i] = *(const half8*)(bsrc0 + i * 8);
    bf[1][i] = *(const half8*)(bsrc1 + i * 8);
    bf[2][i] = *(const half8*)(bsrc2 + i * 8);
  }

  for (int k0 = 0; k0 < 1024; k0 += 64) {
    {
      half4_t h;
      h[0] = (_Float16)af.x; h[1] = (_Float16)af.y;
      h[2] = (_Float16)af.z; h[3] = (_Float16)af.w;
      *(half4_t*)&A_lds[arow * 72 + ac0] = h;
    }
#pragma unroll
    for (int p = 0; p < 3; p++)
#pragma unroll
      for (int i = 0; i < 2; i++)
        *(half8*)&B_lds[(p * 128 + brow) * 72 + bc0 + i * 8] = bf[p][i];
    __syncthreads();

    // prefetch next k-slice into registers (latency overlaps MFMA phase)
    if (k0 + 64 < 1024) {
      af = *(const float4*)(asrc + k0 + 64);
#pragma unroll
      for (int i = 0; i < 2; i++) {
        bf[0][i] = *(const half8*)(bsrc0 + k0 + 64 + i * 8);
        bf[1][i] = *(const half8*)(bsrc1 + k0 + 64 + i * 8);
        bf[2][i] = *(const half8*)(bsrc2 + k0 + 64 + i * 8);
      }
    }

    half8 a[2][2];
#pragma unroll
    for (int mi = 0; mi < 2; mi++)
#pragma unroll
      for (int kc = 0; kc < 2; kc++)
        a[mi][kc] = *(const half8*)&A_lds[(mi * 16 + l16) * 72 + kc * 32 + quad * 8];
    int nw = w * 48;
#pragma unroll
    for (int ni = 0; ni < 3; ni++)
#pragma unroll
      for (int kc = 0; kc < 2; kc++) {
        half8 b = *(const half8*)&B_lds[(nw + ni * 16 + l16) * 72 + kc * 32 + quad * 8];
        acc[0][ni] = MFMA16(a[0][kc], b, acc[0][ni]);
        acc[1][ni] = MFMA16(a[1][kc], b, acc[1][ni]);
      }
    __syncthreads();
  }

  // Epilogue: Q/K stored directly; V columns go through LDS transpose.
  _Float16* Vl = B_lds;  // [128 cols][pad 40]; B_lds dead after last barrier
#pragma unroll
  for (int mi = 0; mi < 2; mi++)
#pragma unroll
    for (int ni = 0; ni < 3; ni++) {
      int nb = w * 48 + ni * 16;
#pragma unroll
      for (int r = 0; r < 4; r++) {
        int row = m0 + mi * 16 + quad * 4 + r;
        _Float16 v = (_Float16)acc[mi][ni][r];
        if (nb < 128)
          Qh[(size_t)row * 128 + nb + l16] = v;
        else if (nb < 256)
          Kh[(size_t)row * 128 + nb - 128 + l16] = v;
        else
          Vl[(nb - 256 + l16) * 40 + mi * 16 + quad * 4 + r] = v;
      }
    }
  __syncthreads();
  if (tid < 256) {
    int col = tid >> 1, hh = tid & 1;
    int bb = m0 >> 11, s0 = (m0 & 2047) + hh * 16;
    half8 h0 = *(half8*)&Vl[col * 40 + hh * 16];
    half8 h1 = *(half8*)&Vl[col * 40 + hh * 16 + 8];
    _Float16* dstv = Vt + ((size_t)(bb * 128 + col)) * 2048 + s0;
    *(half8*)&dstv[0] = h0;
    *(half8*)&dstv[8] = h1;
  }
}

// ---------------------------------------------------------------------------
// Kernel 3: flash-attention partial, one 256-key chunk per block, processed
// as two 128-key sub-chunks with online softmax. 576 blocks, all co-resident
// at 3 blocks/CU. K staged in LDS; V prefetched to registers during K-phase.
// (Exact R3 source -- best measured config, 146.8 us.)
// ---------------------------------------------------------------------------
__global__ __launch_bounds__(256, 3) void attn_partial(
    const _Float16* __restrict__ Qh, const _Float16* __restrict__ Kh,
    const _Float16* __restrict__ Vt, _Float16* __restrict__ Opart,
    float* __restrict__ Ml) {
  __shared__ _Float16 KV_lds[128 * 136];  // K (key-major), then V (feat-major)
  __shared__ _Float16 P_lds[4 * 16 * 136];
  int tid = threadIdx.x;
  int w = tid >> 6, lane = tid & 63, quad = lane >> 4, l16 = lane & 15;
  int g = (int)blockIdx.x;
  int b = g & 3;
  int r = g >> 2;  // 0..143: group m has 4 qtiles x (m+1) chunks, offset 2m(m+1)
  int m = (int)sqrtf((float)r * 0.5f);
  while (2 * m * (m + 1) > r) m--;
  while (2 * (m + 1) * (m + 2) <= r) m++;
  int r0_ = r - 2 * m * (m + 1);
  int qdiv = r0_ / (m + 1);
  int qt = 4 * m + qdiv;
  int kc = r0_ - qdiv * (m + 1);
  int q0 = qt * 64, k0 = kc * 256;
  int kmax = (qt + 1) * 64;
  int len = kmax - k0; if (len > 256) len = 256;
  int nsub = (len + 127) >> 7;  // 1 or 2
  int qw0 = q0 + w * 16;
  int sidx = (b * 32 + qt) * 8 + kc;

  const _Float16* Kb = Kh + (size_t)b * 2048 * 128;
  const _Float16* Vb = Vt + (size_t)b * 128 * 2048;

  half8 aq[4];
  {
    const _Float16* qbase = Qh + (size_t)(b * 2048 + qw0 + l16) * 128;
#pragma unroll
    for (int c = 0; c < 4; c++) aq[c] = *(const half8*)&qbase[c * 32 + quad * 8];
  }

  int srow = tid >> 1, scol = (tid & 1) * 64;
  floatx4 zero = {0.f, 0.f, 0.f, 0.f};
  floatx4 O[8];
#pragma unroll
  for (int t = 0; t < 8; t++) O[t] = zero;
  float m_r[4] = {MASKVAL, MASKVAL, MASKVAL, MASKVAL};
  float l_r[4] = {0.f, 0.f, 0.f, 0.f};

  for (int s = 0; s < nsub; s++) {
    int ks = k0 + s * 128;
    if (s) __syncthreads();  // prev PV done with KV_lds/P_lds
#pragma unroll
    for (int i = 0; i < 8; i++)
      *(half8*)&KV_lds[srow * 136 + scol + i * 8] =
          *(const half8*)&Kb[(size_t)(ks + srow) * 128 + scol + i * 8];
    half8 vreg[8];
#pragma unroll
    for (int i = 0; i < 8; i++)
      vreg[i] = *(const half8*)&Vb[(size_t)srow * 2048 + ks + scol + i * 8];
    __syncthreads();

    floatx4 sa[8];
#pragma unroll
    for (int t = 0; t < 8; t++) sa[t] = zero;
#pragma unroll
    for (int t = 0; t < 8; t++)
#pragma unroll
      for (int c = 0; c < 4; c++) {
        half8 bk = *(const half8*)&KV_lds[(t * 16 + l16) * 136 + c * 32 + quad * 8];
        sa[t] = MFMA16(aq[c], bk, sa[t]);
      }

    float sc[4];
#pragma unroll
    for (int j = 0; j < 4; j++) {
      int query = qw0 + quad * 4 + j;
      float mx = MASKVAL;
#pragma unroll
      for (int t = 0; t < 8; t++) {
        float v = (ks + t * 16 + l16 > query) ? MASKVAL : sa[t][j];
        sa[t][j] = v;
        mx = fmaxf(mx, v);
      }
#pragma unroll
      for (int off = 1; off < 16; off <<= 1) mx = fmaxf(mx, __shfl_xor(mx, off));
      float mnew = fmaxf(m_r[j], mx);
      float scj = exp2f(m_r[j] - mnew);
      float rs = 0.f;
#pragma unroll
      for (int t = 0; t < 8; t++) {
        float e = exp2f(sa[t][j] - mnew);
        sa[t][j] = e;
        rs += e;
      }
#pragma unroll
      for (int off = 1; off < 16; off <<= 1) rs += __shfl_xor(rs, off);
      l_r[j] = l_r[j] * scj + rs;
      m_r[j] = mnew;
      sc[j] = scj;
    }
    // rescale running O by per-row correction before accumulating this chunk
#pragma unroll
    for (int t = 0; t < 8; t++)
#pragma unroll
      for (int j = 0; j < 4; j++) O[t][j] *= sc[j];

    __syncthreads();  // all waves done reading K from KV_lds
#pragma unroll
    for (int i = 0; i < 8; i++)
      *(half8*)&KV_lds[srow * 136 + scol + i * 8] = vreg[i];
    _Float16* P = P_lds + w * 16 * 136;
#pragma unroll
    for (int j = 0; j < 4; j++)
#pragma unroll
      for (int t = 0; t < 8; t++)
        P[(quad * 4 + j) * 136 + t * 16 + l16] = (_Float16)sa[t][j];
    __syncthreads();  // V,P visible to all waves

#pragma unroll
    for (int c2 = 0; c2 < 4; c2++) {
      half8 ap = *(const half8*)&P[l16 * 136 + c2 * 32 + quad * 8];
#pragma unroll
      for (int t = 0; t < 8; t++) {
        half8 bv = *(const half8*)&KV_lds[(t * 16 + l16) * 136 + c2 * 32 + quad * 8];
        O[t] = MFMA16(ap, bv, O[t]);
      }
    }
  }

  size_t obase = (size_t)sidx * 8192;
#pragma unroll
  for (int t = 0; t < 8; t++)
#pragma unroll
    for (int j = 0; j < 4; j++)
      Opart[obase + (size_t)(w * 16 + quad * 4 + j) * 128 + t * 16 + l16] = (_Float16)O[t][j];
  if (l16 == 0)
#pragma unroll
    for (int j = 0; j < 4; j++) {
      int row = w * 16 + quad * 4 + j;
      floatx2 ml;
      ml[0] = m_r[j];
      ml[1] = l_r[j];
      *(floatx2*)&Ml[(size_t)sidx * 128 + row * 2] = ml;
    }
}

// ---------------------------------------------------------------------------
// Kernel 4 (fused combine + out-projection): 256 blocks x 32 rows.
// Combine <=8 partials into LDS ctx tile, then GEMM vs wot over 8 n-chunks
// with register-prefetched B staging. (Exact R3 source.)
// ---------------------------------------------------------------------------
__global__ __launch_bounds__(256) void combine_out(
    const _Float16* __restrict__ Opart, const float* __restrict__ Ml,
    const _Float16* __restrict__ wot, float* __restrict__ out) {
  __shared__ _Float16 A_lds[32 * 136];
  __shared__ _Float16 B_lds[128 * 136];
  int tid = threadIdx.x;
  int r0 = blockIdx.x * 32;
  int b = r0 >> 11, s0 = r0 & 2047;
  int qt = s0 >> 6, rbase = s0 & 63;
  int nkc = (qt + 4) >> 2;  // ceil((qt+1)/4), block-uniform
  int sidx0 = (b * 32 + qt) * 8;

  {  // ---- combine phase: each thread = 1 row x 16 cols ----
    int lr = tid >> 3, c0 = (tid & 7) * 16;
    int ri = rbase + lr;
    float mv[8], lv[8];
#pragma unroll
    for (int i = 0; i < 8; i++) {
      if (i < nkc) {
        floatx2 ml = *(const floatx2*)&Ml[(size_t)(sidx0 + i) * 128 + ri * 2];
        mv[i] = ml[0]; lv[i] = ml[1];
      } else { mv[i] = MASKVAL; lv[i] = 0.f; }
    }
    float M = MASKVAL;
#pragma unroll
    for (int i = 0; i < 8; i++) M = fmaxf(M, mv[i]);
    float L = 0.f;
    float a0[16];
#pragma unroll
    for (int c = 0; c < 16; c++) a0[c] = 0.f;
#pragma unroll
    for (int i = 0; i < 8; i++) {
      if (i < nkc) {
        float scv = exp2f(mv[i] - M);
        L += lv[i] * scv;
        const _Float16* op = &Opart[(size_t)(sidx0 + i) * 8192 + (size_t)ri * 128 + c0];
        half8 o0 = *(const half8*)&op[0];
        half8 o1 = *(const half8*)&op[8];
#pragma unroll
        for (int c = 0; c < 8; c++) {
          a0[c]     += scv * (float)o0[c];
          a0[8 + c] += scv * (float)o1[c];
        }
      }
    }
    float inv = 1.f / L;
    half8 h0, h1;
#pragma unroll
    for (int c = 0; c < 8; c++) {
      h0[c] = (_Float16)(a0[c] * inv);
      h1[c] = (_Float16)(a0[8 + c] * inv);
    }
    *(half8*)&A_lds[lr * 136 + c0] = h0;
    *(half8*)&A_lds[lr * 136 + c0 + 8] = h1;
  }

  int w = tid >> 6, lane = tid & 63, quad = lane >> 4, l16 = lane & 15;
  int bn = tid >> 1, bk = (tid & 1) * 64;
  half8 bf[8];
#pragma unroll
  for (int i = 0; i < 8; i++)
    bf[i] = *(const half8*)&wot[(size_t)bn * 128 + bk + i * 8];
  __syncthreads();  // A_lds ready

  half8 a[2][4];
#pragma unroll
  for (int c = 0; c < 4; c++) {
    a[0][c] = *(const half8*)&A_lds[l16 * 136 + c * 32 + quad * 8];
    a[1][c] = *(const half8*)&A_lds[(16 + l16) * 136 + c * 32 + quad * 8];
  }
  floatx4 zero = {0.f, 0.f, 0.f, 0.f};
  for (int nc = 0; nc < 8; nc++) {
#pragma unroll
    for (int i = 0; i < 8; i++)
      *(half8*)&B_lds[bn * 136 + bk + i * 8] = bf[i];
    __syncthreads();
    if (nc < 7) {
#pragma unroll
      for (int i = 0; i < 8; i++)
        bf[i] = *(const half8*)&wot[(size_t)((nc + 1) * 128 + bn) * 128 + bk + i * 8];
    }
    floatx4 acc[2][2];
#pragma unroll
    for (int mi = 0; mi < 2; mi++)
#pragma unroll
      for (int ni = 0; ni < 2; ni++) acc[mi][ni] = zero;
    int nw = w * 32;
#pragma unroll
    for (int ni = 0; ni < 2; ni++)
#pragma unroll
      for (int c = 0; c < 4; c++) {
        half8 bb = *(const half8*)&B_lds[(nw + ni * 16 + l16) * 136 + c * 32 + quad * 8];
        acc[0][ni] = MFMA16(a[0][c], bb, acc[0][ni]);
        acc[1][ni] = MFMA16(a[1][c], bb, acc[1][ni]);
      }
#pragma unroll
    for (int mi = 0; mi < 2; mi++)
#pragma unroll
      for (int ni = 0; ni < 2; ni++)
#pragma unroll
        for (int r = 0; r < 4; r++) {
          int row = r0 + mi * 16 + quad * 4 + r;
          out[(size_t)row * 1024 + nc * 128 + nw + ni * 16 + l16] = acc[mi][ni][r];
        }
    __syncthreads();
  }
}

// ---------------------------------------------------------------------------
extern "C" void kernel_launch(void* const* d_in, const int* in_sizes, int n_in,
                              void* d_out, int out_size, void* d_ws, size_t ws_size,
                              hipStream_t stream) {
  const float* x = (const float*)d_in[0];
  const float* wq = (const float*)d_in[1];
  const float* wk = (const float*)d_in[2];
  const float* wv = (const float*)d_in[3];
  const float* wo = (const float*)d_in[4];
  char* ws = (char*)d_ws;
  _Float16* wqt = (_Float16*)(ws + 0);
  _Float16* wkt = (_Float16*)(ws + 262144);
  _Float16* wvt = (_Float16*)(ws + 524288);
  _Float16* wot = (_Float16*)(ws + 786432);
  _Float16* Qh  = (_Float16*)(ws + 1048576);              // 2 MB
  _Float16* Kh  = (_Float16*)(ws + 3145728);              // 2 MB
  _Float16* Vt  = (_Float16*)(ws + 5242880);              // 2 MB
  _Float16* Opart = (_Float16*)(ws + 9437184);            // 1024 x 16 KB = 16 MB
  float* Ml = (float*)(ws + 26214400);                    // 512 KB
  float* out = (float*)d_out;

  wprep<<<512, 256, 0, stream>>>(wq, wk, wv, wo, wqt, wkt, wvt, wot);
  qkv_fused<<<256, 512, 0, stream>>>(x, wqt, wkt, wvt, Qh, Kh, Vt);
  attn_partial<<<576, 256, 0, stream>>>(Qh, Kh, Vt, Opart, Ml);
  combine_out<<<256, 256, 0, stream>>>(Opart, Ml, wot, out);
}

// Round 8
// 146.305 us; speedup vs baseline: 1.0999x; 1.0156x over previous
//
#include <hip/hip_runtime.h>
#include <hip/hip_bf16.h>
#include <math.h>

typedef _Float16 half8 __attribute__((ext_vector_type(8)));
typedef _Float16 half4_t __attribute__((ext_vector_type(4)));
typedef _Float16 half2_t __attribute__((ext_vector_type(2)));
typedef float floatx4 __attribute__((ext_vector_type(4)));
typedef float floatx2 __attribute__((ext_vector_type(2)));

#define MFMA16(a, b, c) __builtin_amdgcn_mfma_f32_16x16x32_f16(a, b, c, 0, 0, 0)
#define MASKVAL (-30000.0f)
// 1/sqrt(128) * log2(e), folded into wqt during prep
#define QSCALE 0.1275261529f

// ---------------------------------------------------------------------------
// Kernel 1: coalesced LDS-tiled weight transpose + fp32->fp16 convert.
// ---------------------------------------------------------------------------
__global__ __launch_bounds__(256) void wprep(
    const float* __restrict__ wq, const float* __restrict__ wk,
    const float* __restrict__ wv, const float* __restrict__ wo,
    _Float16* __restrict__ wqt, _Float16* __restrict__ wkt,
    _Float16* __restrict__ wvt, _Float16* __restrict__ wot) {
  __shared__ float T[32][36];
  int bx = blockIdx.x, tid = threadIdx.x;
  const float* src;
  _Float16* dst;
  int R, C, r0, c0;
  float sc = 1.0f;
  if (bx < 384) {
    int p = bx >> 7, t = bx & 127;
    src = (p == 0) ? wq : (p == 1) ? wk : wv;
    dst = (p == 0) ? wqt : (p == 1) ? wkt : wvt;
    if (p == 0) sc = QSCALE;
    R = 1024; C = 128;
    r0 = (t & 31) * 32; c0 = (t >> 5) * 32;
  } else {
    int t = bx - 384;
    src = wo; dst = wot;
    R = 128; C = 1024;
    r0 = (t & 3) * 32; c0 = (t >> 2) * 32;
  }
  {
    int row = tid >> 3, c4 = (tid & 7) * 4;
    float4 f = *(const float4*)&src[(size_t)(r0 + row) * C + c0 + c4];
    T[row][c4] = f.x; T[row][c4 + 1] = f.y; T[row][c4 + 2] = f.z; T[row][c4 + 3] = f.w;
  }
  __syncthreads();
  {
    int cc = tid >> 3, r4 = (tid & 7) * 4;
    half4_t h;
    h[0] = (_Float16)(T[r4 + 0][cc] * sc);
    h[1] = (_Float16)(T[r4 + 1][cc] * sc);
    h[2] = (_Float16)(T[r4 + 2][cc] * sc);
    h[3] = (_Float16)(T[r4 + 3][cc] * sc);
    *(half4_t*)&dst[(size_t)(c0 + cc) * R + r0 + r4] = h;
  }
}

// ---------------------------------------------------------------------------
// Kernel 2: FUSED QKV projection -- reads x exactly ONCE. 256 blocks x 512
// threads (8 waves). Tile: 32 rows x 384 cols (Q|K|V). BK=64, 16 k-steps.
// (Exact R3/R7 source -- best measured config.)
// ---------------------------------------------------------------------------
__global__ __launch_bounds__(512, 4) void qkv_fused(
    const float* __restrict__ x, const _Float16* __restrict__ wqt,
    const _Float16* __restrict__ wkt, const _Float16* __restrict__ wvt,
    _Float16* __restrict__ Qh, _Float16* __restrict__ Kh,
    _Float16* __restrict__ Vt) {
  __shared__ _Float16 A_lds[32 * 72];
  __shared__ _Float16 B_lds[384 * 72];
  int tid = threadIdx.x;
  int w = tid >> 6, lane = tid & 63, quad = lane >> 4, l16 = lane & 15;
  int m0 = blockIdx.x * 32;
  floatx4 zero = {0.f, 0.f, 0.f, 0.f};
  floatx4 acc[2][3];
#pragma unroll
  for (int mi = 0; mi < 2; mi++)
#pragma unroll
    for (int ni = 0; ni < 3; ni++) acc[mi][ni] = zero;

  int arow = tid >> 4, ac0 = (tid & 15) * 4;   // A: 32 rows, 4 floats/thr
  int brow = tid >> 2, bc0 = (tid & 3) * 16;   // B: 128 rows/proj, 16 halfs/thr/proj

  const float* asrc = x + (size_t)(m0 + arow) * 1024 + ac0;
  const _Float16* bsrc0 = wqt + (size_t)brow * 1024 + bc0;
  const _Float16* bsrc1 = wkt + (size_t)brow * 1024 + bc0;
  const _Float16* bsrc2 = wvt + (size_t)brow * 1024 + bc0;

  float4 af;
  half8 bf[3][2];
  af = *(const float4*)asrc;
#pragma unroll
  for (int i = 0; i < 2; i++) {
    bf[0][i] = *(const half8*)(bsrc0 + i * 8);
    bf[1][i] = *(const half8*)(bsrc1 + i * 8);
    bf[2][i] = *(const half8*)(bsrc2 + i * 8);
  }

  for (int k0 = 0; k0 < 1024; k0 += 64) {
    {
      half4_t h;
      h[0] = (_Float16)af.x; h[1] = (_Float16)af.y;
      h[2] = (_Float16)af.z; h[3] = (_Float16)af.w;
      *(half4_t*)&A_lds[arow * 72 + ac0] = h;
    }
#pragma unroll
    for (int p = 0; p < 3; p++)
#pragma unroll
      for (int i = 0; i < 2; i++)
        *(half8*)&B_lds[(p * 128 + brow) * 72 + bc0 + i * 8] = bf[p][i];
    __syncthreads();

    // prefetch next k-slice into registers (latency overlaps MFMA phase)
    if (k0 + 64 < 1024) {
      af = *(const float4*)(asrc + k0 + 64);
#pragma unroll
      for (int i = 0; i < 2; i++) {
        bf[0][i] = *(const half8*)(bsrc0 + k0 + 64 + i * 8);
        bf[1][i] = *(const half8*)(bsrc1 + k0 + 64 + i * 8);
        bf[2][i] = *(const half8*)(bsrc2 + k0 + 64 + i * 8);
      }
    }

    half8 a[2][2];
#pragma unroll
    for (int mi = 0; mi < 2; mi++)
#pragma unroll
      for (int kc = 0; kc < 2; kc++)
        a[mi][kc] = *(const half8*)&A_lds[(mi * 16 + l16) * 72 + kc * 32 + quad * 8];
    int nw = w * 48;
#pragma unroll
    for (int ni = 0; ni < 3; ni++)
#pragma unroll
      for (int kc = 0; kc < 2; kc++) {
        half8 b = *(const half8*)&B_lds[(nw + ni * 16 + l16) * 72 + kc * 32 + quad * 8];
        acc[0][ni] = MFMA16(a[0][kc], b, acc[0][ni]);
        acc[1][ni] = MFMA16(a[1][kc], b, acc[1][ni]);
      }
    __syncthreads();
  }

  // Epilogue: Q/K stored directly; V columns go through LDS transpose.
  _Float16* Vl = B_lds;  // [128 cols][pad 40]; B_lds dead after last barrier
#pragma unroll
  for (int mi = 0; mi < 2; mi++)
#pragma unroll
    for (int ni = 0; ni < 3; ni++) {
      int nb = w * 48 + ni * 16;
#pragma unroll
      for (int r = 0; r < 4; r++) {
        int row = m0 + mi * 16 + quad * 4 + r;
        _Float16 v = (_Float16)acc[mi][ni][r];
        if (nb < 128)
          Qh[(size_t)row * 128 + nb + l16] = v;
        else if (nb < 256)
          Kh[(size_t)row * 128 + nb - 128 + l16] = v;
        else
          Vl[(nb - 256 + l16) * 40 + mi * 16 + quad * 4 + r] = v;
      }
    }
  __syncthreads();
  if (tid < 256) {
    int col = tid >> 1, hh = tid & 1;
    int bb = m0 >> 11, s0 = (m0 & 2047) + hh * 16;
    half8 h0 = *(half8*)&Vl[col * 40 + hh * 16];
    half8 h1 = *(half8*)&Vl[col * 40 + hh * 16 + 8];
    _Float16* dstv = Vt + ((size_t)(bb * 128 + col)) * 2048 + s0;
    *(half8*)&dstv[0] = h0;
    *(half8*)&dstv[8] = h1;
  }
}

// ---------------------------------------------------------------------------
// Kernel 3: flash-attention partial, 256-key chunk per block (two 128-key
// sub-chunks, online softmax), 576 blocks. SWAPPED-OPERAND QK^T: computes
// MFMA(K, Q) so the query sits on the MFMA *column* axis -> lane holds
// S[key = ks+t*16+quad*4+j][q = qw0+l16]. Same LDS reads (A/B fragments
// have identical per-lane layouts), but:
//   - softmax m/l are per-lane scalars; cross-quad reduce = 2 shfl_xor
//     (16,32) instead of 4x4 in-row shuffles (32 -> 4 shfls/thread);
//   - P packs j=0..3 into half4 -> 8 ds_write_b64 (was 32 ds_write_u16),
//     and P is wave-private (each wave reads back only its own q-rows);
//   - PV also swapped (MFMA(V,P)) -> O[q=l16][d=t*16+quad*4+j]; Opart
//     stores pack to 8 x half4 (was 32 scalar u16 stores).
// Opart/Ml formats unchanged; combine_out untouched.
// ---------------------------------------------------------------------------
__global__ __launch_bounds__(256, 3) void attn_partial(
    const _Float16* __restrict__ Qh, const _Float16* __restrict__ Kh,
    const _Float16* __restrict__ Vt, _Float16* __restrict__ Opart,
    float* __restrict__ Ml) {
  __shared__ _Float16 KV_lds[128 * 136];  // K (key-major), then V (feat-major)
  __shared__ _Float16 P_lds[4 * 16 * 136];  // per-wave 16x136, wave-private
  int tid = threadIdx.x;
  int w = tid >> 6, lane = tid & 63, quad = lane >> 4, l16 = lane & 15;
  int g = (int)blockIdx.x;
  int b = g & 3;
  int r = g >> 2;  // 0..143: group m has 4 qtiles x (m+1) chunks, offset 2m(m+1)
  int m = (int)sqrtf((float)r * 0.5f);
  while (2 * m * (m + 1) > r) m--;
  while (2 * (m + 1) * (m + 2) <= r) m++;
  int r0_ = r - 2 * m * (m + 1);
  int qdiv = r0_ / (m + 1);
  int qt = 4 * m + qdiv;
  int kc = r0_ - qdiv * (m + 1);
  int q0 = qt * 64, k0 = kc * 256;
  int kmax = (qt + 1) * 64;
  int len = kmax - k0; if (len > 256) len = 256;
  int nsub = (len + 127) >> 7;  // 1 or 2
  int qw0 = q0 + w * 16;
  int query = qw0 + l16;  // lane-fixed query row
  int sidx = (b * 32 + qt) * 8 + kc;

  const _Float16* Kb = Kh + (size_t)b * 2048 * 128;
  const _Float16* Vb = Vt + (size_t)b * 128 * 2048;

  half8 aq[4];
  {
    const _Float16* qbase = Qh + (size_t)(b * 2048 + query) * 128;
#pragma unroll
    for (int c = 0; c < 4; c++) aq[c] = *(const half8*)&qbase[c * 32 + quad * 8];
  }

  int srow = tid >> 1, scol = (tid & 1) * 64;
  floatx4 zero = {0.f, 0.f, 0.f, 0.f};
  floatx4 O[8];  // O[t][j] = O[q=query][d = t*16 + quad*4 + j]
#pragma unroll
  for (int t = 0; t < 8; t++) O[t] = zero;
  float m_r = MASKVAL, l_r = 0.f;

  for (int s = 0; s < nsub; s++) {
    int ks = k0 + s * 128;
    if (s) __syncthreads();  // prev PV done with KV_lds/P_lds
#pragma unroll
    for (int i = 0; i < 8; i++)
      *(half8*)&KV_lds[srow * 136 + scol + i * 8] =
          *(const half8*)&Kb[(size_t)(ks + srow) * 128 + scol + i * 8];
    half8 vreg[8];
#pragma unroll
    for (int i = 0; i < 8; i++)
      vreg[i] = *(const half8*)&Vb[(size_t)srow * 2048 + ks + scol + i * 8];
    __syncthreads();

    // swapped QK^T: sa[t][j] = S[key = ks + t*16 + quad*4 + j][q = query]
    floatx4 sa[8];
#pragma unroll
    for (int t = 0; t < 8; t++) sa[t] = zero;
#pragma unroll
    for (int t = 0; t < 8; t++)
#pragma unroll
      for (int c = 0; c < 4; c++) {
        half8 bk = *(const half8*)&KV_lds[(t * 16 + l16) * 136 + c * 32 + quad * 8];
        sa[t] = MFMA16(bk, aq[c], sa[t]);
      }

    // mask + per-lane max (4 parallel chains), then cross-quad reduce
    float mx0 = MASKVAL, mx1 = MASKVAL, mx2 = MASKVAL, mx3 = MASKVAL;
#pragma unroll
    for (int t = 0; t < 8; t++) {
      int kb = ks + t * 16 + quad * 4;
      float v0 = (kb + 0 > query) ? MASKVAL : sa[t][0];
      float v1 = (kb + 1 > query) ? MASKVAL : sa[t][1];
      float v2 = (kb + 2 > query) ? MASKVAL : sa[t][2];
      float v3 = (kb + 3 > query) ? MASKVAL : sa[t][3];
      sa[t][0] = v0; sa[t][1] = v1; sa[t][2] = v2; sa[t][3] = v3;
      mx0 = fmaxf(mx0, v0); mx1 = fmaxf(mx1, v1);
      mx2 = fmaxf(mx2, v2); mx3 = fmaxf(mx3, v3);
    }
    float mx = fmaxf(fmaxf(mx0, mx1), fmaxf(mx2, mx3));
    mx = fmaxf(mx, __shfl_xor(mx, 16));
    mx = fmaxf(mx, __shfl_xor(mx, 32));
    float mnew = fmaxf(m_r, mx);
    float scj = exp2f(m_r - mnew);
    float rs0 = 0.f, rs1 = 0.f, rs2 = 0.f, rs3 = 0.f;
#pragma unroll
    for (int t = 0; t < 8; t++) {
      float e0 = exp2f(sa[t][0] - mnew); sa[t][0] = e0; rs0 += e0;
      float e1 = exp2f(sa[t][1] - mnew); sa[t][1] = e1; rs1 += e1;
      float e2 = exp2f(sa[t][2] - mnew); sa[t][2] = e2; rs2 += e2;
      float e3 = exp2f(sa[t][3] - mnew); sa[t][3] = e3; rs3 += e3;
    }
    float rs = (rs0 + rs1) + (rs2 + rs3);
    rs += __shfl_xor(rs, 16);
    rs += __shfl_xor(rs, 32);
    l_r = l_r * scj + rs;
    m_r = mnew;
    // rescale running O by the per-lane correction
#pragma unroll
    for (int t = 0; t < 8; t++)
#pragma unroll
      for (int j = 0; j < 4; j++) O[t][j] *= scj;

    __syncthreads();  // all waves done reading K from KV_lds
#pragma unroll
    for (int i = 0; i < 8; i++)
      *(half8*)&KV_lds[srow * 136 + scol + i * 8] = vreg[i];
    // P write: wave-private, packed half4 per key-tile
    _Float16* P = P_lds + w * 16 * 136;
#pragma unroll
    for (int t = 0; t < 8; t++) {
      half4_t p4;
      p4[0] = (_Float16)sa[t][0];
      p4[1] = (_Float16)sa[t][1];
      p4[2] = (_Float16)sa[t][2];
      p4[3] = (_Float16)sa[t][3];
      *(half4_t*)&P[l16 * 136 + t * 16 + quad * 4] = p4;
    }
    __syncthreads();  // V visible to all waves

    // swapped PV: O[t] += MFMA(A = V^T rows d, B = P[q][keys])
#pragma unroll
    for (int c2 = 0; c2 < 4; c2++) {
      half8 bp = *(const half8*)&P[l16 * 136 + c2 * 32 + quad * 8];
#pragma unroll
      for (int t = 0; t < 8; t++) {
        half8 av = *(const half8*)&KV_lds[(t * 16 + l16) * 136 + c2 * 32 + quad * 8];
        O[t] = MFMA16(av, bp, O[t]);
      }
    }
  }

  // Opart write: lane holds row q=qw0+l16, cols t*16+quad*4..+3 -> half4
  size_t obase = (size_t)sidx * 8192 + (size_t)(w * 16 + l16) * 128;
#pragma unroll
  for (int t = 0; t < 8; t++) {
    half4_t o4;
    o4[0] = (_Float16)O[t][0];
    o4[1] = (_Float16)O[t][1];
    o4[2] = (_Float16)O[t][2];
    o4[3] = (_Float16)O[t][3];
    *(half4_t*)&Opart[obase + t * 16 + quad * 4] = o4;
  }
  if (lane < 16) {
    floatx2 ml;
    ml[0] = m_r;
    ml[1] = l_r;
    *(floatx2*)&Ml[(size_t)sidx * 128 + (w * 16 + l16) * 2] = ml;
  }
}

// ---------------------------------------------------------------------------
// Kernel 4 (fused combine + out-projection): 256 blocks x 32 rows.
// (Exact R3/R7 source.)
// ---------------------------------------------------------------------------
__global__ __launch_bounds__(256) void combine_out(
    const _Float16* __restrict__ Opart, const float* __restrict__ Ml,
    const _Float16* __restrict__ wot, float* __restrict__ out) {
  __shared__ _Float16 A_lds[32 * 136];
  __shared__ _Float16 B_lds[128 * 136];
  int tid = threadIdx.x;
  int r0 = blockIdx.x * 32;
  int b = r0 >> 11, s0 = r0 & 2047;
  int qt = s0 >> 6, rbase = s0 & 63;
  int nkc = (qt + 4) >> 2;  // ceil((qt+1)/4), block-uniform
  int sidx0 = (b * 32 + qt) * 8;

  {  // ---- combine phase: each thread = 1 row x 16 cols ----
    int lr = tid >> 3, c0 = (tid & 7) * 16;
    int ri = rbase + lr;
    float mv[8], lv[8];
#pragma unroll
    for (int i = 0; i < 8; i++) {
      if (i < nkc) {
        floatx2 ml = *(const floatx2*)&Ml[(size_t)(sidx0 + i) * 128 + ri * 2];
        mv[i] = ml[0]; lv[i] = ml[1];
      } else { mv[i] = MASKVAL; lv[i] = 0.f; }
    }
    float M = MASKVAL;
#pragma unroll
    for (int i = 0; i < 8; i++) M = fmaxf(M, mv[i]);
    float L = 0.f;
    float a0[16];
#pragma unroll
    for (int c = 0; c < 16; c++) a0[c] = 0.f;
#pragma unroll
    for (int i = 0; i < 8; i++) {
      if (i < nkc) {
        float scv = exp2f(mv[i] - M);
        L += lv[i] * scv;
        const _Float16* op = &Opart[(size_t)(sidx0 + i) * 8192 + (size_t)ri * 128 + c0];
        half8 o0 = *(const half8*)&op[0];
        half8 o1 = *(const half8*)&op[8];
#pragma unroll
        for (int c = 0; c < 8; c++) {
          a0[c]     += scv * (float)o0[c];
          a0[8 + c] += scv * (float)o1[c];
        }
      }
    }
    float inv = 1.f / L;
    half8 h0, h1;
#pragma unroll
    for (int c = 0; c < 8; c++) {
      h0[c] = (_Float16)(a0[c] * inv);
      h1[c] = (_Float16)(a0[8 + c] * inv);
    }
    *(half8*)&A_lds[lr * 136 + c0] = h0;
    *(half8*)&A_lds[lr * 136 + c0 + 8] = h1;
  }

  int w = tid >> 6, lane = tid & 63, quad = lane >> 4, l16 = lane & 15;
  int bn = tid >> 1, bk = (tid & 1) * 64;
  half8 bf[8];
#pragma unroll
  for (int i = 0; i < 8; i++)
    bf[i] = *(const half8*)&wot[(size_t)bn * 128 + bk + i * 8];
  __syncthreads();  // A_lds ready

  half8 a[2][4];
#pragma unroll
  for (int c = 0; c < 4; c++) {
    a[0][c] = *(const half8*)&A_lds[l16 * 136 + c * 32 + quad * 8];
    a[1][c] = *(const half8*)&A_lds[(16 + l16) * 136 + c * 32 + quad * 8];
  }
  floatx4 zero = {0.f, 0.f, 0.f, 0.f};
  for (int nc = 0; nc < 8; nc++) {
#pragma unroll
    for (int i = 0; i < 8; i++)
      *(half8*)&B_lds[bn * 136 + bk + i * 8] = bf[i];
    __syncthreads();
    if (nc < 7) {
#pragma unroll
      for (int i = 0; i < 8; i++)
        bf[i] = *(const half8*)&wot[(size_t)((nc + 1) * 128 + bn) * 128 + bk + i * 8];
    }
    floatx4 acc[2][2];
#pragma unroll
    for (int mi = 0; mi < 2; mi++)
#pragma unroll
      for (int ni = 0; ni < 2; ni++) acc[mi][ni] = zero;
    int nw = w * 32;
#pragma unroll
    for (int ni = 0; ni < 2; ni++)
#pragma unroll
      for (int c = 0; c < 4; c++) {
        half8 bb = *(const half8*)&B_lds[(nw + ni * 16 + l16) * 136 + c * 32 + quad * 8];
        acc[0][ni] = MFMA16(a[0][c], bb, acc[0][ni]);
        acc[1][ni] = MFMA16(a[1][c], bb, acc[1][ni]);
      }
#pragma unroll
    for (int mi = 0; mi < 2; mi++)
#pragma unroll
      for (int ni = 0; ni < 2; ni++)
#pragma unroll
        for (int r = 0; r < 4; r++) {
          int row = r0 + mi * 16 + quad * 4 + r;
          out[(size_t)row * 1024 + nc * 128 + nw + ni * 16 + l16] = acc[mi][ni][r];
        }
    __syncthreads();
  }
}

// ---------------------------------------------------------------------------
extern "C" void kernel_launch(void* const* d_in, const int* in_sizes, int n_in,
                              void* d_out, int out_size, void* d_ws, size_t ws_size,
                              hipStream_t stream) {
  const float* x = (const float*)d_in[0];
  const float* wq = (const float*)d_in[1];
  const float* wk = (const float*)d_in[2];
  const float* wv = (const float*)d_in[3];
  const float* wo = (const float*)d_in[4];
  char* ws = (char*)d_ws;
  _Float16* wqt = (_Float16*)(ws + 0);
  _Float16* wkt = (_Float16*)(ws + 262144);
  _Float16* wvt = (_Float16*)(ws + 524288);
  _Float16* wot = (_Float16*)(ws + 786432);
  _Float16* Qh  = (_Float16*)(ws + 1048576);              // 2 MB
  _Float16* Kh  = (_Float16*)(ws + 3145728);              // 2 MB
  _Float16* Vt  = (_Float16*)(ws + 5242880);              // 2 MB
  _Float16* Opart = (_Float16*)(ws + 9437184);            // 1024 x 16 KB = 16 MB
  float* Ml = (float*)(ws + 26214400);                    // 512 KB
  float* out = (float*)d_out;

  wprep<<<512, 256, 0, stream>>>(wq, wk, wv, wo, wqt, wkt, wvt, wot);
  qkv_fused<<<256, 512, 0, stream>>>(x, wqt, wkt, wvt, Qh, Kh, Vt);
  attn_partial<<<576, 256, 0, stream>>>(Qh, Kh, Vt, Opart, Ml);
  combine_out<<<256, 256, 0, stream>>>(Opart, Ml, wot, out);
}